// Round 7
// baseline (5650.103 us; speedup 1.0000x reference)
//
#include <hip/hip_runtime.h>
#include <math.h>

#define Bn 32
#define Cn 768
#define CRn 192
#define HWn 1024                  // H*W, contiguous innermost per (b,c)
#define ROWS (Bn * Cn)            // 24576
#define RPB 4                     // rows per block (one per wave)
#define NBLK (ROWS / RPB)         // 6144
#define BPB (Cn / RPB)            // blocks per batch = 192

typedef float nfloat4 __attribute__((ext_vector_type(4)));

// Single-dispatch SE via last-block-done: means -> per-batch counter; the
// last-arriving (hence resident) block of each batch computes the MLP gates
// and sets a flag; peers spin briefly, then scale their REGISTER-HELD x rows
// (x is read exactly once from HBM) and nt-stream the output.
__global__ __launch_bounds__(256) void se_fused(const float* __restrict__ x,
                                                const float* __restrict__ w1,
                                                const float* __restrict__ b1,
                                                const float* __restrict__ w2,
                                                const float* __restrict__ b2,
                                                float* __restrict__ out,
                                                float* __restrict__ s,    // [ROWS]
                                                float* __restrict__ g,    // [ROWS]
                                                int* __restrict__ cnt,    // [Bn] zeroed
                                                int* __restrict__ flag) { // [Bn] zeroed
    const int tid  = threadIdx.x;
    const int lane = tid & 63;
    const int wid  = tid >> 6;
    const int b    = blockIdx.x / BPB;
    const int r    = blockIdx.x * RPB + wid;      // this wave's row

    // ---- Phase 1: mean of own row; x stays in registers ----
    const float4* xp = (const float4*)(x + (size_t)r * HWn);
    float4 v0 = xp[lane];
    float4 v1 = xp[lane + 64];
    float4 v2 = xp[lane + 128];
    float4 v3 = xp[lane + 192];
    float sum = (v0.x + v0.y + v0.z + v0.w) + (v1.x + v1.y + v1.z + v1.w)
              + (v2.x + v2.y + v2.z + v2.w) + (v3.x + v3.y + v3.z + v3.w);
    #pragma unroll
    for (int off = 32; off > 0; off >>= 1) sum += __shfl_xor(sum, off);
    if (lane == 0)
        __hip_atomic_store(&s[r], sum * (1.0f / (float)HWn),
                           __ATOMIC_RELAXED, __HIP_MEMORY_SCOPE_AGENT);

    __shared__ int is_last;
    __syncthreads();
    if (tid == 0) {
        __threadfence();  // publish s before the count
        int old = __hip_atomic_fetch_add(&cnt[b], 1, __ATOMIC_ACQ_REL,
                                         __HIP_MEMORY_SCOPE_AGENT);
        is_last = (old == BPB - 1);
    }
    __syncthreads();

    // ---- Phase 2 (one block per batch): MLP -> gates ----
    if (is_last) {
        __shared__ float sl[Cn];
        __shared__ float hl[CRn];
        __threadfence();
        for (int i = tid; i < Cn; i += 256)
            sl[i] = __hip_atomic_load(&s[b * Cn + i], __ATOMIC_RELAXED,
                                      __HIP_MEMORY_SCOPE_AGENT);
        __syncthreads();
        if (tid < CRn) {
            const float4* wr = (const float4*)(w1 + (size_t)tid * Cn);
            const float4* sp = (const float4*)sl;   // broadcast reads, no conflicts
            float acc = 0.0f;
            #pragma unroll 4
            for (int k = 0; k < Cn / 4; ++k) {
                float4 wv = wr[k]; float4 sv = sp[k];
                acc += wv.x * sv.x + wv.y * sv.y + wv.z * sv.z + wv.w * sv.w;
            }
            acc += b1[tid];
            hl[tid] = acc / (1.0f + expf(-acc));    // swish
        }
        __syncthreads();
        for (int c = tid; c < Cn; c += 256) {
            const float4* wr = (const float4*)(w2 + (size_t)c * CRn);
            const float4* hp = (const float4*)hl;
            float acc = 0.0f;
            #pragma unroll 4
            for (int k = 0; k < CRn / 4; ++k) {
                float4 wv = wr[k]; float4 hv = hp[k];
                acc += wv.x * hv.x + wv.y * hv.y + wv.z * hv.z + wv.w * hv.w;
            }
            acc += b2[c];
            __hip_atomic_store(&g[b * Cn + c], 1.0f / (1.0f + expf(-acc)),
                               __ATOMIC_RELAXED, __HIP_MEMORY_SCOPE_AGENT);
        }
        __syncthreads();
        if (tid == 0) {
            __threadfence();
            __hip_atomic_store(&flag[b], 1, __ATOMIC_RELEASE,
                               __HIP_MEMORY_SCOPE_AGENT);
        }
    }

    // ---- Phase 3: wait for own batch's gates (producer is resident) ----
    if (tid == 0) {
        int it = 0;
        while (__hip_atomic_load(&flag[b], __ATOMIC_ACQUIRE,
                                 __HIP_MEMORY_SCOPE_AGENT) == 0) {
            __builtin_amdgcn_s_sleep(16);
            if (++it > (1 << 20)) break;   // safety: never wedge the queue
        }
    }
    __syncthreads();

    const float gv = __hip_atomic_load(&g[r], __ATOMIC_RELAXED,
                                       __HIP_MEMORY_SCOPE_AGENT);
    nfloat4* op = (nfloat4*)(out + (size_t)r * HWn);
    nfloat4 n0 = { v0.x * gv, v0.y * gv, v0.z * gv, v0.w * gv };
    nfloat4 n1 = { v1.x * gv, v1.y * gv, v1.z * gv, v1.w * gv };
    nfloat4 n2 = { v2.x * gv, v2.y * gv, v2.z * gv, v2.w * gv };
    nfloat4 n3 = { v3.x * gv, v3.y * gv, v3.z * gv, v3.w * gv };
    __builtin_nontemporal_store(n0, &op[lane]);
    __builtin_nontemporal_store(n1, &op[lane + 64]);
    __builtin_nontemporal_store(n2, &op[lane + 128]);
    __builtin_nontemporal_store(n3, &op[lane + 192]);
}

extern "C" void kernel_launch(void* const* d_in, const int* in_sizes, int n_in,
                              void* d_out, int out_size, void* d_ws, size_t ws_size,
                              hipStream_t stream) {
    const float* x  = (const float*)d_in[0];
    const float* w1 = (const float*)d_in[1];
    const float* b1 = (const float*)d_in[2];
    const float* w2 = (const float*)d_in[3];
    const float* b2 = (const float*)d_in[4];
    float* out = (float*)d_out;

    float* s   = (float*)d_ws;                 // [ROWS]
    float* g   = s + ROWS;                     // [ROWS]
    int*   cnt = (int*)(g + ROWS);             // [Bn]
    int*   fl  = cnt + Bn;                     // [Bn]

    // zero the 256 B counter/flag region (ws is poisoned 0xAA before each call)
    hipMemsetAsync((void*)cnt, 0, 2 * Bn * sizeof(int), stream);

    void* args[] = { (void*)&x, (void*)&w1, (void*)&b1, (void*)&w2, (void*)&b2,
                     (void*)&out, (void*)&s, (void*)&g, (void*)&cnt, (void*)&fl };
    hipLaunchKernel((void*)se_fused, dim3(NBLK), dim3(256), args, 0, stream);
}